// Round 4
// baseline (354.227 us; speedup 1.0000x reference)
//
#include <hip/hip_runtime.h>

// Output = conv1x1(x, refine_w, refine_b). Everything else in the reference is
// dead code: `_dead` is unused, and x_back == x exactly (permutation followed
// by its argsort-inverse).
//
// x: (8, 64, 256, 256) fp32, refine_w: (64, 64) [o-major], refine_b: (64,)
// out[b,o,h,w] = sum_c w[o,c] * x[b,c,h,w] + b[o]
//
// R1-R3 lesson: the AMDGPU scheduler targets MAX occupancy (8 waves/EU, <=64
// VGPR) and fissions any 64-deep register working set into chunked re-loads
// (R3: VGPR=36, ~8x re-read via L2/L3, 117 us). Fix:
//   (a) amdgpu_waves_per_eu(4,4) pins the pressure target at 128 VGPRs;
//   (b) volatile staging loads are illegal to duplicate -> reload-fission
//       cannot happen; values must stay in registers.
//   (c) o-loop unroll 4 keeps the body ~2 KB (inside I$).

constexpr int  C    = 64;
constexpr long HW   = 65536;      // 256*256
constexpr long NPIX = 8L * HW;    // 524288 pixels total

__global__
__attribute__((amdgpu_flat_work_group_size(256, 256), amdgpu_waves_per_eu(4, 4)))
void conv1x1_refine_kernel(
    const float* __restrict__ x,
    const float* __restrict__ w,     // (64,64) o-major
    const float* __restrict__ bias,  // (64,)
    float* __restrict__ out)
{
    const long tid = (long)blockIdx.x * blockDim.x + threadIdx.x; // one pixel
    const long b   = tid >> 16;            // pixel / HW
    const long hw  = tid & (HW - 1);       // pixel % HW

    const volatile float* __restrict__ xp = x + b * (C * HW) + hw;
    float* op = out + b * (C * HW) + hw;

    // Stage the whole input-channel column in registers. volatile: exactly 64
    // loads, no rematerialization possible. Issued back-to-back -> ~16 KB of
    // memory-level parallelism per wave.
    float xv[C];
#pragma unroll
    for (int c = 0; c < C; ++c) xv[c] = xp[(long)c * HW];

    // One output channel at a time: scalar accumulator, immediate store.
#pragma unroll 4
    for (int o = 0; o < C; ++o) {
        float s = bias[o];                 // uniform -> s_load
#pragma unroll
        for (int c = 0; c < C; ++c) {
            // w address uniform -> SGPR operand of v_fmac
            s = fmaf(w[o * C + c], xv[c], s);
        }
        __builtin_nontemporal_store(s, op + (long)o * HW);
    }
}

extern "C" void kernel_launch(void* const* d_in, const int* in_sizes, int n_in,
                              void* d_out, int out_size, void* d_ws, size_t ws_size,
                              hipStream_t stream)
{
    const float* x  = (const float*)d_in[0];   // x
    const float* rw = (const float*)d_in[11];  // refine_w
    const float* rb = (const float*)d_in[12];  // refine_b
    float* out = (float*)d_out;

    const int threads = 256;
    const int blocks  = (int)(NPIX / threads); // 2048
    hipLaunchKernelGGL(conv1x1_refine_kernel, dim3(blocks), dim3(threads), 0, stream,
                       x, rw, rb, out);
}